// Round 7
// baseline (279.267 us; speedup 1.0000x reference)
//
#include <hip/hip_runtime.h>
#include <hip/hip_bf16.h>

#define B_ 2
#define T_ 2048
#define D_ 1024
#define H_ 16
#define DH_ 64

typedef __attribute__((ext_vector_type(8))) short bf16x8;
typedef __attribute__((ext_vector_type(4))) short bf16x4;
typedef __attribute__((ext_vector_type(4))) float f32x4;
typedef __attribute__((ext_vector_type(8))) unsigned short u16x8;

__device__ __forceinline__ unsigned short f2bf(float f) {   // RNE fp32->bf16
    unsigned int u = __float_as_uint(f);
    return (unsigned short)((u + 0x7FFFu + ((u >> 16) & 1u)) >> 16);
}

__device__ __forceinline__ void pack8(const float4& a, const float4& b, u16x8& o) {
    o[0] = f2bf(a.x); o[1] = f2bf(a.y); o[2] = f2bf(a.z); o[3] = f2bf(a.w);
    o[4] = f2bf(b.x); o[5] = f2bf(b.y); o[6] = f2bf(b.z); o[7] = f2bf(b.w);
}

// K=16 bf16 MFMA; guard so the host pass never touches the builtin.
__device__ __forceinline__ f32x4 mfma16(bf16x4 a, bf16x4 b, f32x4 c) {
#if defined(__HIP_DEVICE_COMPILE__)
    return __builtin_amdgcn_mfma_f32_16x16x16bf16_1k(a, b, c, 0, 0, 0);
#else
    return c;
#endif
}

// ---------------------------------------------------------------------------
// Launch 1: pure streaming conversions (all blocks independent).
//   [0,1024)   : v[b,h,t,dh] -> vt[b,h,dh,t] bf16 (64x64 LDS transpose)
//   [1024,1536): k fp32 -> kb bf16   (32 elems/thread)
//   [1536,2048): x fp32 -> xb bf16   (32 elems/thread)
//   [2048,2176): Wq fp32 -> wqb bf16 (32 elems/thread)
// ---------------------------------------------------------------------------
__global__ __launch_bounds__(256) void conv_kernel(
    const float* __restrict__ k, const float* __restrict__ v,
    const float* __restrict__ x, const float* __restrict__ Wq,
    unsigned short* __restrict__ kb, unsigned short* __restrict__ vt,
    unsigned short* __restrict__ xb, unsigned short* __restrict__ wqb)
{
    __shared__ float Ts[64][65];
    const int tid = threadIdx.x;
    const int bi = blockIdx.x;

    if (bi < 1024) {                      // ---- v transpose+convert ----
        const int t0 = (bi & 31) * 64;
        const int hb = bi >> 5;
        const size_t bh = (size_t)(hb >> 4) * H_ + (hb & 15);
        #pragma unroll
        for (int u = 0; u < 4; ++u) {
            const int tr = u * 16 + (tid >> 4);
            const int dc = (tid & 15) * 4;
            const float4 r = *(const float4*)(v + (bh * T_ + t0 + tr) * DH_ + dc);
            Ts[tr][dc + 0] = r.x; Ts[tr][dc + 1] = r.y;
            Ts[tr][dc + 2] = r.z; Ts[tr][dc + 3] = r.w;
        }
        __syncthreads();
        #pragma unroll
        for (int u = 0; u < 4; ++u) {
            const int dh = u * 16 + (tid >> 4);
            const int tc = (tid & 15) * 4;
            ushort4 o;
            o.x = f2bf(Ts[tc + 0][dh]); o.y = f2bf(Ts[tc + 1][dh]);
            o.z = f2bf(Ts[tc + 2][dh]); o.w = f2bf(Ts[tc + 3][dh]);
            *(ushort4*)(vt + (bh * DH_ + dh) * T_ + t0 + tc) = o;
        }
        return;
    }

    const float* src;
    unsigned short* dst;
    if (bi < 1536)      { src = k  + ((size_t)(bi - 1024) * 256 + tid) * 32;
                          dst = kb  + ((size_t)(bi - 1024) * 256 + tid) * 32; }
    else if (bi < 2048) { src = x  + ((size_t)(bi - 1536) * 256 + tid) * 32;
                          dst = xb  + ((size_t)(bi - 1536) * 256 + tid) * 32; }
    else                { src = Wq + ((size_t)(bi - 2048) * 256 + tid) * 32;
                          dst = wqb + ((size_t)(bi - 2048) * 256 + tid) * 32; }
    #pragma unroll
    for (int u = 0; u < 4; ++u) {
        const float4 a = *(const float4*)(src + u * 8);
        const float4 b = *(const float4*)(src + u * 8 + 4);
        u16x8 o; pack8(a, b, o);
        *(u16x8*)(dst + u * 8) = o;
    }
}

// ---------------------------------------------------------------------------
// Launch 2: mega-attention. Per block (qt,h,b):
//   Phase 1: build Q^T = Wq_h * x^T via MFMA, fragments straight from global
//            (wqb slice is L2-resident, xb rows L1-resident). C-layout has
//            col=qrow — exactly the transposed-S convention. One LDS bounce
//            (overlaid on K/V buffer 1, dead until iter-0 prefetch) converts
//            to B-fragment layout; Q scale folds in 1/sqrt(D) * log2(e).
//   Phase 2: transposed-S flash loop (R6), softmax in exp2 domain,
//            double-buffered K/V (stride 68: conflict-free fragment reads).
// ---------------------------------------------------------------------------
__global__ __launch_bounds__(256, 4) void attn_kernel(
    const unsigned short* __restrict__ xb,   // [B,T,D]   bf16
    const unsigned short* __restrict__ wqb,  // [D,D]     bf16
    const unsigned short* __restrict__ kb,   // [B,H,T,DH] bf16
    const unsigned short* __restrict__ vt,   // [B,H,DH,T] bf16
    const float* __restrict__ xg,            // [B,T,D] fp32 (residual)
    float* __restrict__ out)                 // [B,T,D] fp32
{
    __shared__ __align__(16) char lds_raw[34816];
    unsigned short (*Ks0)[68] = (unsigned short(*)[68])(lds_raw);
    unsigned short (*Vs0)[68] = (unsigned short(*)[68])(lds_raw + 8704);
    unsigned short (*Ks1)[68] = (unsigned short(*)[68])(lds_raw + 17408);
    unsigned short (*Vs1)[68] = (unsigned short(*)[68])(lds_raw + 26112);
    unsigned short (*Qs)[68]  = (unsigned short(*)[68])(lds_raw + 17408); // overlay

    const int tid = threadIdx.x;
    const int lane = tid & 63;
    const int w = tid >> 6;
    const int l15 = lane & 15, l4 = lane >> 4;
    const int bi = blockIdx.x;
    const int qt = 31 - (bi >> 5);           // heavy q-tiles dispatch first
    const int hb = bi & 31;
    const int h = hb & 15, b = hb >> 4;
    const int q0 = qt * 64;
    const size_t bh = (size_t)b * H_ + h;

    // ---- Phase 1: Q^T build. acc[mt]: dh = mt*16+l4*4+r, qrow(local) = l15
    {
        f32x4 acc[4] = {};
        const unsigned short* xr  = xb  + ((size_t)b * T_ + q0 + w * 16 + l15) * D_ + l4 * 8;
        const unsigned short* wr0 = wqb + (size_t)(h * 64 + l15) * D_ + l4 * 8;
        #pragma unroll 4
        for (int kk = 0; kk < D_; kk += 32) {
            const bf16x8 xf = *(const bf16x8*)(xr + kk);
            #pragma unroll
            for (int mt = 0; mt < 4; ++mt) {
                const bf16x8 wf = *(const bf16x8*)(wr0 + (size_t)(mt * 16) * D_ + kk);
                acc[mt] = __builtin_amdgcn_mfma_f32_16x16x32_bf16(wf, xf, acc[mt], 0, 0, 0);
            }
        }
        const float qscale = 1.4426950408889634f / 32.0f;  // log2(e)/sqrt(D)
        #pragma unroll
        for (int mt = 0; mt < 4; ++mt) {
            ushort4 o;
            o.x = f2bf(acc[mt][0] * qscale); o.y = f2bf(acc[mt][1] * qscale);
            o.z = f2bf(acc[mt][2] * qscale); o.w = f2bf(acc[mt][3] * qscale);
            *(ushort4*)&Qs[w * 16 + l15][mt * 16 + l4 * 4] = o;
        }
    }
    // read Q B-fragments (wave-private rows; compiler inserts lgkmcnt wait)
    bf16x8 qf[2];
    #pragma unroll
    for (int kc = 0; kc < 2; ++kc)
        qf[kc] = *(const bf16x8*)&Qs[w * 16 + l15][kc * 32 + l4 * 8];

    f32x4 o_acc[4] = {};                     // O^T: dh = mt*16+l4*4+r, qrow = l15
    float m_i = -INFINITY, l_i = 0.0f;

    const int srow = tid >> 2;               // staging 0..63
    const int scol = (tid & 3) * 16;

    // stage tile j0=0 into buffer 0
    {
        const unsigned short* gk = kb + (bh * T_ + srow) * DH_ + scol;
        *(uint4*)&Ks0[srow][scol] = *(const uint4*)gk;
        *(uint4*)&Ks0[srow][scol + 8] = *(const uint4*)(gk + 8);
        const unsigned short* gv = vt + (bh * DH_ + srow) * T_ + scol;
        *(uint4*)&Vs0[srow][scol] = *(const uint4*)gv;
        *(uint4*)&Vs0[srow][scol + 8] = *(const uint4*)(gv + 8);
    }
    __syncthreads();   // Qs reads complete before anyone overwrites overlay

    int p = 0;
    for (int j0 = 0; j0 <= q0; j0 += 64) {
        unsigned short (*Ksp)[68] = p ? Ks1 : Ks0;
        unsigned short (*Vsp)[68] = p ? Vs1 : Vs0;
        unsigned short (*Ksn)[68] = p ? Ks0 : Ks1;
        unsigned short (*Vsn)[68] = p ? Vs0 : Vs1;

        // prefetch next tile into registers (valid-but-discarded addr on last)
        const int jn = (j0 + 64 <= q0) ? j0 + 64 : 0;
        uint4 kr0, kr1, vr0, vr1;
        {
            const unsigned short* gk = kb + (bh * T_ + jn + srow) * DH_ + scol;
            kr0 = *(const uint4*)gk;
            kr1 = *(const uint4*)(gk + 8);
            const unsigned short* gv = vt + (bh * DH_ + srow) * T_ + jn + scol;
            vr0 = *(const uint4*)gv;
            vr1 = *(const uint4*)(gv + 8);
        }

        // S^T = K * Q^T : st[nt] keys nt*16 + l4*4+r, qrow = w*16+l15
        f32x4 st[4] = {};
        #pragma unroll
        for (int kc = 0; kc < 2; ++kc) {
            #pragma unroll
            for (int nt = 0; nt < 4; ++nt) {
                const bf16x8 kf = *(const bf16x8*)&Ksp[nt * 16 + l15][kc * 32 + l4 * 8];
                st[nt] = __builtin_amdgcn_mfma_f32_16x16x32_bf16(kf, qf[kc], st[nt], 0, 0, 0);
            }
        }

        // causal mask (diagonal tile only)
        if (j0 == q0) {
            const int thr = w * 16 + l15 - l4 * 4;   // mask if nt*16+r > thr
            #pragma unroll
            for (int nt = 0; nt < 4; ++nt)
                #pragma unroll
                for (int r = 0; r < 4; ++r)
                    if (nt * 16 + r > thr) st[nt][r] = -INFINITY;
        }

        // online softmax in exp2 domain: 16 in-lane values + 2-shfl butterfly
        float rm = -INFINITY;
        #pragma unroll
        for (int nt = 0; nt < 4; ++nt)
            #pragma unroll
            for (int r = 0; r < 4; ++r) rm = fmaxf(rm, st[nt][r]);
        rm = fmaxf(rm, __shfl_xor(rm, 16));
        rm = fmaxf(rm, __shfl_xor(rm, 32));
        const float mn = fmaxf(m_i, rm);
        const float alpha = exp2f(m_i - mn);
        float rs = 0.0f;
        #pragma unroll
        for (int nt = 0; nt < 4; ++nt)
            #pragma unroll
            for (int r = 0; r < 4; ++r) {
                const float pv = exp2f(st[nt][r] - mn);
                st[nt][r] = pv;
                rs += pv;
            }
        rs += __shfl_xor(rs, 16);
        rs += __shfl_xor(rs, 32);
        l_i = l_i * alpha + rs;
        m_i = mn;
        #pragma unroll
        for (int mt = 0; mt < 4; ++mt)
            #pragma unroll
            for (int r = 0; r < 4; ++r) o_acc[mt][r] *= alpha;

        // pack P^T into K=16 B-frags (v_perm truncation, 2 vals/op)
        bf16x4 pf[4];
        #pragma unroll
        for (int nt = 0; nt < 4; ++nt) {
            union { unsigned int u[2]; bf16x4 s; } cv;
            cv.u[0] = __builtin_amdgcn_perm(__float_as_uint(st[nt][1]),
                                            __float_as_uint(st[nt][0]), 0x07060302u);
            cv.u[1] = __builtin_amdgcn_perm(__float_as_uint(st[nt][3]),
                                            __float_as_uint(st[nt][2]), 0x07060302u);
            pf[nt] = cv.s;
        }

        // O^T += V^T * P^T  (A = V^T from LDS, B = P^T in registers)
        #pragma unroll
        for (int c = 0; c < 4; ++c) {
            #pragma unroll
            for (int mt = 0; mt < 4; ++mt) {
                const bf16x4 vf = *(const bf16x4*)&Vsp[mt * 16 + l15][c * 16 + l4 * 4];
                o_acc[mt] = mfma16(vf, pf[c], o_acc[mt]);
            }
        }

        // write prefetched tile to the other buffer, single barrier
        *(uint4*)&Ksn[srow][scol] = kr0;
        *(uint4*)&Ksn[srow][scol + 8] = kr1;
        *(uint4*)&Vsn[srow][scol] = vr0;
        *(uint4*)&Vsn[srow][scol + 8] = vr1;
        __syncthreads();
        p ^= 1;
    }

    // epilogue: out = x + O^T / l   (dh = mt*16 + l4*4+r, qrow = l15)
    const float inv = 1.0f / l_i;
    const int qrow = q0 + w * 16 + l15;
    #pragma unroll
    for (int mt = 0; mt < 4; ++mt) {
        #pragma unroll
        for (int r = 0; r < 4; ++r) {
            const int d = h * DH_ + mt * 16 + l4 * 4 + r;
            const size_t off = ((size_t)b * T_ + qrow) * D_ + d;
            out[off] = xg[off] + o_acc[mt][r] * inv;
        }
    }
}

extern "C" void kernel_launch(void* const* d_in, const int* in_sizes, int n_in,
                              void* d_out, int out_size, void* d_ws, size_t ws_size,
                              hipStream_t stream) {
    const float* x  = (const float*)d_in[0];
    const float* k  = (const float*)d_in[1];
    const float* v  = (const float*)d_in[2];
    const float* Wq = (const float*)d_in[3];
    float* out = (float*)d_out;

    const size_t NE = (size_t)B_ * H_ * T_ * DH_;   // 4M elements
    unsigned short* kb  = (unsigned short*)d_ws;    // 8 MB
    unsigned short* vt  = kb + NE;                  // 8 MB
    unsigned short* xb  = vt + NE;                  // 8 MB
    unsigned short* wqb = xb + NE;                  // 2 MB

    conv_kernel<<<2176, 256, 0, stream>>>(k, v, x, Wq, kb, vt, xb, wqb);
    attn_kernel<<<1024, 256, 0, stream>>>(xb, wqb, kb, vt, x, out);
}

// Round 8
// 258.951 us; speedup vs baseline: 1.0785x; 1.0785x over previous
//
#include <hip/hip_runtime.h>
#include <hip/hip_bf16.h>

#define B_ 2
#define T_ 2048
#define D_ 1024
#define H_ 16
#define DH_ 64

typedef __attribute__((ext_vector_type(8))) short bf16x8;
typedef __attribute__((ext_vector_type(4))) short bf16x4;
typedef __attribute__((ext_vector_type(4))) float f32x4;
typedef __attribute__((ext_vector_type(8))) unsigned short u16x8;

__device__ __forceinline__ unsigned short f2bf(float f) {   // RNE fp32->bf16
    unsigned int u = __float_as_uint(f);
    return (unsigned short)((u + 0x7FFFu + ((u >> 16) & 1u)) >> 16);
}

__device__ __forceinline__ void pack8(const float4& a, const float4& b, u16x8& o) {
    o[0] = f2bf(a.x); o[1] = f2bf(a.y); o[2] = f2bf(a.z); o[3] = f2bf(a.w);
    o[4] = f2bf(b.x); o[5] = f2bf(b.y); o[6] = f2bf(b.z); o[7] = f2bf(b.w);
}

// K=16 bf16 MFMA; guard so the host pass never touches the builtin.
__device__ __forceinline__ f32x4 mfma16(bf16x4 a, bf16x4 b, f32x4 c) {
#if defined(__HIP_DEVICE_COMPILE__)
    return __builtin_amdgcn_mfma_f32_16x16x16bf16_1k(a, b, c, 0, 0, 0);
#else
    return c;
#endif
}

// ---------------------------------------------------------------------------
// Launch 1 (fused; heavy qproj blocks dispatch FIRST):
//   [0,512)    : qproj 128(M)x64(N=head) tile, BK=32, dbuf staging,
//                1 barrier/iter -> qb bf16 [B,H,T,DH], scale log2e/sqrt(D)
//   [512,1024) : k fp32 -> kb bf16 (32 elems/thread)
//   [1024,2048): v[b,h,t,dh] -> vt[b,h,dh,t] bf16 (64x64 LDS transpose)
// ---------------------------------------------------------------------------
__global__ __launch_bounds__(256) void fused_prep_qproj(
    const float* __restrict__ k, const float* __restrict__ v,
    const float* __restrict__ x, const float* __restrict__ Wq,
    unsigned short* __restrict__ kb, unsigned short* __restrict__ vt,
    unsigned short* __restrict__ qb)
{
    __shared__ __align__(16) char lds_raw[30720];
    const int tid = threadIdx.x;
    const int bi = blockIdx.x;

    if (bi >= 512 && bi < 1024) {         // ---- k conversion ----
        const int idx = bi - 512;
        const float* src = k + ((size_t)idx * 256 + tid) * 32;
        unsigned short* dst = kb + ((size_t)idx * 256 + tid) * 32;
        #pragma unroll
        for (int u = 0; u < 4; ++u) {
            const float4 a = *(const float4*)(src + u * 8);
            const float4 b = *(const float4*)(src + u * 8 + 4);
            u16x8 o; pack8(a, b, o);
            *(u16x8*)(dst + u * 8) = o;
        }
        return;
    }

    if (bi >= 1024) {                     // ---- v transpose+convert ----
        float (*Ts)[65] = (float(*)[65])lds_raw;
        const int idx = bi - 1024;
        const int t0 = (idx & 31) * 64;
        const int hb = idx >> 5;
        const size_t bh = (size_t)(hb >> 4) * H_ + (hb & 15);
        #pragma unroll
        for (int u = 0; u < 4; ++u) {
            const int tr = u * 16 + (tid >> 4);
            const int dc = (tid & 15) * 4;
            const float4 r = *(const float4*)(v + (bh * T_ + t0 + tr) * DH_ + dc);
            Ts[tr][dc + 0] = r.x; Ts[tr][dc + 1] = r.y;
            Ts[tr][dc + 2] = r.z; Ts[tr][dc + 3] = r.w;
        }
        __syncthreads();
        #pragma unroll
        for (int u = 0; u < 4; ++u) {
            const int dh = u * 16 + (tid >> 4);
            const int tc = (tid & 15) * 4;
            ushort4 o;
            o.x = f2bf(Ts[tc + 0][dh]); o.y = f2bf(Ts[tc + 1][dh]);
            o.z = f2bf(Ts[tc + 2][dh]); o.w = f2bf(Ts[tc + 3][dh]);
            *(ushort4*)(vt + (bh * DH_ + dh) * T_ + t0 + tc) = o;
        }
        return;
    }

    // ---- qproj: 128x64 tile, BK=32, reg-prefetch dbuf, 1 barrier/iter ----
    // LDS: Xs[2][128][40] bf16 (10240 B each), Ws[2][64][40] (5120 B each)
    unsigned short (*Xs0)[40] = (unsigned short(*)[40])(lds_raw);
    unsigned short (*Xs1)[40] = (unsigned short(*)[40])(lds_raw + 10240);
    unsigned short (*Ws0)[40] = (unsigned short(*)[40])(lds_raw + 20480);
    unsigned short (*Ws1)[40] = (unsigned short(*)[40])(lds_raw + 25600);

    const int m0 = (bi >> 4) * 128;       // 32 m-tiles over B*T
    const int h  = bi & 15;               // n-tile == head
    const int lane = tid & 63;
    const int w = tid >> 6;
    const int l15 = lane & 15, l4 = lane >> 4;

    const int xrow = tid >> 1, xcol = (tid & 1) * 16;   // 16 floats/thread
    const int wrow = tid >> 2, wcol = (tid & 3) * 8;    // 8 floats/thread

    const float* xg0 = x  + (size_t)(m0 + xrow) * D_ + xcol;
    const float* wg0 = Wq + (size_t)(h * 64 + wrow) * D_ + wcol;

    f32x4 acc[2][4] = {};

    // stage iter 0 into buffer 0
    float4 xr0 = *(const float4*)(xg0);
    float4 xr1 = *(const float4*)(xg0 + 4);
    float4 xr2 = *(const float4*)(xg0 + 8);
    float4 xr3 = *(const float4*)(xg0 + 12);
    float4 wr0 = *(const float4*)(wg0);
    float4 wr1 = *(const float4*)(wg0 + 4);
    {
        u16x8 p0, p1, pw;
        pack8(xr0, xr1, p0); pack8(xr2, xr3, p1); pack8(wr0, wr1, pw);
        *(u16x8*)&Xs0[xrow][xcol] = p0;
        *(u16x8*)&Xs0[xrow][xcol + 8] = p1;
        *(u16x8*)&Ws0[wrow][wcol] = pw;
    }
    __syncthreads();

    int p = 0;
    for (int it = 0; it < 32; ++it) {
        // prefetch next K-slice into registers
        if (it < 31) {
            const int kk = (it + 1) * 32;
            xr0 = *(const float4*)(xg0 + kk);
            xr1 = *(const float4*)(xg0 + kk + 4);
            xr2 = *(const float4*)(xg0 + kk + 8);
            xr3 = *(const float4*)(xg0 + kk + 12);
            wr0 = *(const float4*)(wg0 + kk);
            wr1 = *(const float4*)(wg0 + kk + 4);
        }

        unsigned short (*Xp)[40] = p ? Xs1 : Xs0;
        unsigned short (*Wp)[40] = p ? Ws1 : Ws0;
        bf16x8 af[2], bfr[4];
        #pragma unroll
        for (int mt = 0; mt < 2; ++mt)
            af[mt] = *(const bf16x8*)&Xp[w * 32 + mt * 16 + l15][l4 * 8];
        #pragma unroll
        for (int nt = 0; nt < 4; ++nt)
            bfr[nt] = *(const bf16x8*)&Wp[nt * 16 + l15][l4 * 8];
        #pragma unroll
        for (int mt = 0; mt < 2; ++mt)
            #pragma unroll
            for (int nt = 0; nt < 4; ++nt)
                acc[mt][nt] = __builtin_amdgcn_mfma_f32_16x16x32_bf16(af[mt], bfr[nt], acc[mt][nt], 0, 0, 0);

        if (it < 31) {
            unsigned short (*Xn)[40] = p ? Xs0 : Xs1;
            unsigned short (*Wn)[40] = p ? Ws0 : Ws1;
            u16x8 p0, p1, pw;
            pack8(xr0, xr1, p0); pack8(xr2, xr3, p1); pack8(wr0, wr1, pw);
            *(u16x8*)&Xn[xrow][xcol] = p0;
            *(u16x8*)&Xn[xrow][xcol + 8] = p1;
            *(u16x8*)&Wn[wrow][wcol] = pw;
            __syncthreads();
            p ^= 1;
        }
    }

    const float qscale = 1.4426950408889634f / 32.0f;   // log2(e)/sqrt(D)
    #pragma unroll
    for (int mt = 0; mt < 2; ++mt) {
        #pragma unroll
        for (int nt = 0; nt < 4; ++nt) {
            const int dh = nt * 16 + l15;
            #pragma unroll
            for (int r = 0; r < 4; ++r) {
                const int m = m0 + w * 32 + mt * 16 + l4 * 4 + r;
                const int b = m >> 11, t = m & 2047;
                qb[(((size_t)b * H_ + h) * T_ + t) * DH_ + dh] = f2bf(acc[mt][nt][r] * qscale);
            }
        }
    }
}

// ---------------------------------------------------------------------------
// Launch 2: transposed-S MFMA flash attention + residual (R6 structure).
// 64 q-rows/block (4 waves x 16 rows), 1024 blocks, heavy tiles first.
// S^T = K*Q^T (softmax: 1 scalar/lane + 2 shfls, exp2 domain). P^T stays in
// registers (S^T C-layout == K=16 B-operand layout). O^T = V^T * P^T.
// Double-buffered K/V, stride 68 (measured zero bank conflicts), 1 barrier.
// ---------------------------------------------------------------------------
__global__ __launch_bounds__(256, 4) void attn_kernel(
    const unsigned short* __restrict__ qb,   // [B,H,T,DH] bf16, scale log2e/32
    const unsigned short* __restrict__ kb,   // [B,H,T,DH] bf16
    const unsigned short* __restrict__ vt,   // [B,H,DH,T] bf16
    const float* __restrict__ xg,            // [B,T,D] fp32 (residual)
    float* __restrict__ out)                 // [B,T,D] fp32
{
    __shared__ __align__(16) char lds_raw[34816];
    unsigned short (*Ks0)[68] = (unsigned short(*)[68])(lds_raw);
    unsigned short (*Vs0)[68] = (unsigned short(*)[68])(lds_raw + 8704);
    unsigned short (*Ks1)[68] = (unsigned short(*)[68])(lds_raw + 17408);
    unsigned short (*Vs1)[68] = (unsigned short(*)[68])(lds_raw + 26112);

    const int tid = threadIdx.x;
    const int lane = tid & 63;
    const int w = tid >> 6;
    const int l15 = lane & 15, l4 = lane >> 4;
    const int bi = blockIdx.x;
    const int qt = 31 - (bi >> 5);           // heavy q-tiles dispatch first
    const int hb = bi & 31;
    const int h = hb & 15, b = hb >> 4;
    const int q0 = qt * 64;
    const size_t bh = (size_t)b * H_ + h;

    // Q fragments (B-operand: lane l15 = qrow, k = dh); one-time load
    bf16x8 qf[2];
    #pragma unroll
    for (int kc = 0; kc < 2; ++kc)
        qf[kc] = *(const bf16x8*)(qb + (bh * T_ + q0 + w * 16 + l15) * DH_ + kc * 32 + l4 * 8);

    f32x4 o_acc[4] = {};                     // O^T: dh = mt*16+l4*4+r, qrow = l15
    float m_i = -INFINITY, l_i = 0.0f;

    const int srow = tid >> 2;               // staging 0..63
    const int scol = (tid & 3) * 16;

    // stage tile j0=0 into buffer 0
    {
        const unsigned short* gk = kb + (bh * T_ + srow) * DH_ + scol;
        *(uint4*)&Ks0[srow][scol] = *(const uint4*)gk;
        *(uint4*)&Ks0[srow][scol + 8] = *(const uint4*)(gk + 8);
        const unsigned short* gv = vt + (bh * DH_ + srow) * T_ + scol;
        *(uint4*)&Vs0[srow][scol] = *(const uint4*)gv;
        *(uint4*)&Vs0[srow][scol + 8] = *(const uint4*)(gv + 8);
    }
    __syncthreads();

    int p = 0;
    for (int j0 = 0; j0 <= q0; j0 += 64) {
        unsigned short (*Ksp)[68] = p ? Ks1 : Ks0;
        unsigned short (*Vsp)[68] = p ? Vs1 : Vs0;
        unsigned short (*Ksn)[68] = p ? Ks0 : Ks1;
        unsigned short (*Vsn)[68] = p ? Vs0 : Vs1;

        // prefetch next tile into registers (valid-but-discarded addr on last)
        const int jn = (j0 + 64 <= q0) ? j0 + 64 : 0;
        uint4 kr0, kr1, vr0, vr1;
        {
            const unsigned short* gk = kb + (bh * T_ + jn + srow) * DH_ + scol;
            kr0 = *(const uint4*)gk;
            kr1 = *(const uint4*)(gk + 8);
            const unsigned short* gv = vt + (bh * DH_ + srow) * T_ + jn + scol;
            vr0 = *(const uint4*)gv;
            vr1 = *(const uint4*)(gv + 8);
        }

        // S^T = K * Q^T : st[nt] keys nt*16 + l4*4+r, qrow = w*16+l15
        f32x4 st[4] = {};
        #pragma unroll
        for (int kc = 0; kc < 2; ++kc) {
            #pragma unroll
            for (int nt = 0; nt < 4; ++nt) {
                const bf16x8 kf = *(const bf16x8*)&Ksp[nt * 16 + l15][kc * 32 + l4 * 8];
                st[nt] = __builtin_amdgcn_mfma_f32_16x16x32_bf16(kf, qf[kc], st[nt], 0, 0, 0);
            }
        }

        // causal mask (diagonal tile only)
        if (j0 == q0) {
            const int thr = w * 16 + l15 - l4 * 4;   // mask if nt*16+r > thr
            #pragma unroll
            for (int nt = 0; nt < 4; ++nt)
                #pragma unroll
                for (int r = 0; r < 4; ++r)
                    if (nt * 16 + r > thr) st[nt][r] = -INFINITY;
        }

        // online softmax, exp2 domain: 16 in-lane values + 2-shfl butterfly
        float rm = -INFINITY;
        #pragma unroll
        for (int nt = 0; nt < 4; ++nt)
            #pragma unroll
            for (int r = 0; r < 4; ++r) rm = fmaxf(rm, st[nt][r]);
        rm = fmaxf(rm, __shfl_xor(rm, 16));
        rm = fmaxf(rm, __shfl_xor(rm, 32));
        const float mn = fmaxf(m_i, rm);
        const float alpha = exp2f(m_i - mn);
        float rs = 0.0f;
        #pragma unroll
        for (int nt = 0; nt < 4; ++nt)
            #pragma unroll
            for (int r = 0; r < 4; ++r) {
                const float pv = exp2f(st[nt][r] - mn);
                st[nt][r] = pv;
                rs += pv;
            }
        rs += __shfl_xor(rs, 16);
        rs += __shfl_xor(rs, 32);
        l_i = l_i * alpha + rs;
        m_i = mn;
        #pragma unroll
        for (int mt = 0; mt < 4; ++mt)
            #pragma unroll
            for (int r = 0; r < 4; ++r) o_acc[mt][r] *= alpha;

        // pack P^T into K=16 B-frags (v_perm truncation, 2 vals/op)
        bf16x4 pf[4];
        #pragma unroll
        for (int nt = 0; nt < 4; ++nt) {
            union { unsigned int u[2]; bf16x4 s; } cv;
            cv.u[0] = __builtin_amdgcn_perm(__float_as_uint(st[nt][1]),
                                            __float_as_uint(st[nt][0]), 0x07060302u);
            cv.u[1] = __builtin_amdgcn_perm(__float_as_uint(st[nt][3]),
                                            __float_as_uint(st[nt][2]), 0x07060302u);
            pf[nt] = cv.s;
        }

        // O^T += V^T * P^T  (A = V^T from LDS, B = P^T in registers)
        #pragma unroll
        for (int c = 0; c < 4; ++c) {
            #pragma unroll
            for (int mt = 0; mt < 4; ++mt) {
                const bf16x4 vf = *(const bf16x4*)&Vsp[mt * 16 + l15][c * 16 + l4 * 4];
                o_acc[mt] = mfma16(vf, pf[c], o_acc[mt]);
            }
        }

        // write prefetched tile to the other buffer, single barrier
        *(uint4*)&Ksn[srow][scol] = kr0;
        *(uint4*)&Ksn[srow][scol + 8] = kr1;
        *(uint4*)&Vsn[srow][scol] = vr0;
        *(uint4*)&Vsn[srow][scol + 8] = vr1;
        __syncthreads();
        p ^= 1;
    }

    // epilogue: out = x + O^T / l   (dh = mt*16 + l4*4+r, qrow = l15)
    const float inv = 1.0f / l_i;
    const int qrow = q0 + w * 16 + l15;
    #pragma unroll
    for (int mt = 0; mt < 4; ++mt) {
        #pragma unroll
        for (int r = 0; r < 4; ++r) {
            const int d = h * DH_ + mt * 16 + l4 * 4 + r;
            const size_t off = ((size_t)b * T_ + qrow) * D_ + d;
            out[off] = xg[off] + o_acc[mt][r] * inv;
        }
    }
}

extern "C" void kernel_launch(void* const* d_in, const int* in_sizes, int n_in,
                              void* d_out, int out_size, void* d_ws, size_t ws_size,
                              hipStream_t stream) {
    const float* x  = (const float*)d_in[0];
    const float* k  = (const float*)d_in[1];
    const float* v  = (const float*)d_in[2];
    const float* Wq = (const float*)d_in[3];
    float* out = (float*)d_out;

    const size_t NE = (size_t)B_ * H_ * T_ * DH_;   // 4M elements
    unsigned short* kb = (unsigned short*)d_ws;     // 8 MB
    unsigned short* vt = kb + NE;                   // 8 MB
    unsigned short* qb = vt + NE;                   // 8 MB

    fused_prep_qproj<<<2048, 256, 0, stream>>>(k, v, x, Wq, kb, vt, qb);
    attn_kernel<<<1024, 256, 0, stream>>>(qb, kb, vt, x, out);
}

// Round 9
// 197.010 us; speedup vs baseline: 1.4175x; 1.3144x over previous
//
#include <hip/hip_runtime.h>
#include <hip/hip_bf16.h>

#define B_ 2
#define T_ 2048
#define D_ 1024
#define H_ 16
#define DH_ 64

typedef __attribute__((ext_vector_type(8))) short bf16x8;
typedef __attribute__((ext_vector_type(4))) short bf16x4;
typedef __attribute__((ext_vector_type(4))) float f32x4;
typedef __attribute__((ext_vector_type(8))) unsigned short u16x8;

__device__ __forceinline__ unsigned short f2bf(float f) {   // RNE fp32->bf16
    unsigned int u = __float_as_uint(f);
    return (unsigned short)((u + 0x7FFFu + ((u >> 16) & 1u)) >> 16);
}

__device__ __forceinline__ void pack8(const float4& a, const float4& b, u16x8& o) {
    o[0] = f2bf(a.x); o[1] = f2bf(a.y); o[2] = f2bf(a.z); o[3] = f2bf(a.w);
    o[4] = f2bf(b.x); o[5] = f2bf(b.y); o[6] = f2bf(b.z); o[7] = f2bf(b.w);
}

// K=16 bf16 MFMA; guard so the host pass never touches the builtin.
__device__ __forceinline__ f32x4 mfma16(bf16x4 a, bf16x4 b, f32x4 c) {
#if defined(__HIP_DEVICE_COMPILE__)
    return __builtin_amdgcn_mfma_f32_16x16x16bf16_1k(a, b, c, 0, 0, 0);
#else
    return c;
#endif
}

// ---------------------------------------------------------------------------
// Launch 1 (fused; heavy qproj blocks dispatch FIRST):
//   [0,1024)   : qproj 64(M)x64(N=head) tile, BK=128 (8 iters),
//                LDS stride 136 shorts = 272 B (16B-aligned, 2-way-free)
//   [1024,1536): k fp32 -> kb bf16 (32 elems/thread)
//   [1536,2560): v[b,h,t,dh] -> vt[b,h,dh,t] bf16 (64x64 LDS transpose)
// ---------------------------------------------------------------------------
__global__ __launch_bounds__(256) void fused_prep_qproj(
    const float* __restrict__ k, const float* __restrict__ v,
    const float* __restrict__ x, const float* __restrict__ Wq,
    unsigned short* __restrict__ kb, unsigned short* __restrict__ vt,
    unsigned short* __restrict__ qb)
{
    __shared__ __align__(16) char lds_raw[34816];
    const int tid = threadIdx.x;
    const int bi = blockIdx.x;

    if (bi >= 1024 && bi < 1536) {        // ---- k conversion ----
        const int idx = bi - 1024;
        const float* src = k + ((size_t)idx * 256 + tid) * 32;
        unsigned short* dst = kb + ((size_t)idx * 256 + tid) * 32;
        #pragma unroll
        for (int u = 0; u < 4; ++u) {
            const float4 a = *(const float4*)(src + u * 8);
            const float4 b = *(const float4*)(src + u * 8 + 4);
            u16x8 o; pack8(a, b, o);
            *(u16x8*)(dst + u * 8) = o;
        }
        return;
    }

    if (bi >= 1536) {                     // ---- v transpose+convert ----
        float (*Ts)[65] = (float(*)[65])lds_raw;
        const int idx = bi - 1536;
        const int t0 = (idx & 31) * 64;
        const int hb = idx >> 5;
        const size_t bh = (size_t)(hb >> 4) * H_ + (hb & 15);
        #pragma unroll
        for (int u = 0; u < 4; ++u) {
            const int tr = u * 16 + (tid >> 4);
            const int dc = (tid & 15) * 4;
            const float4 r = *(const float4*)(v + (bh * T_ + t0 + tr) * DH_ + dc);
            Ts[tr][dc + 0] = r.x; Ts[tr][dc + 1] = r.y;
            Ts[tr][dc + 2] = r.z; Ts[tr][dc + 3] = r.w;
        }
        __syncthreads();
        #pragma unroll
        for (int u = 0; u < 4; ++u) {
            const int dh = u * 16 + (tid >> 4);
            const int tc = (tid & 15) * 4;
            ushort4 o;
            o.x = f2bf(Ts[tc + 0][dh]); o.y = f2bf(Ts[tc + 1][dh]);
            o.z = f2bf(Ts[tc + 2][dh]); o.w = f2bf(Ts[tc + 3][dh]);
            *(ushort4*)(vt + (bh * DH_ + dh) * T_ + t0 + tc) = o;
        }
        return;
    }

    // ---- qproj: 64x64 tile, BK=128, 8 iterations ----
    // As/Bs: 64 rows x 136 shorts (272 B row: 16B-aligned; bank quads
    // advance 4 per row -> 2 lanes/bank on fragment reads = free)
    unsigned short (*As)[136] = (unsigned short(*)[136])(lds_raw);
    unsigned short (*Bs)[136] = (unsigned short(*)[136])(lds_raw + 17408);

    const int m0 = (bi >> 4) * 64;        // 64 m-tiles over B*T
    const int h  = bi & 15;               // n-tile == head
    const int lane = tid & 63;
    const int w = tid >> 6;
    const int l15 = lane & 15, l4 = lane >> 4;

    const int row = tid >> 2;             // staging row 0..63
    const int c   = (tid & 3) * 32;       // staging col (fp32 elems)

    const float* xg0 = x  + (size_t)(m0 + row) * D_ + c;
    const float* wg0 = Wq + (size_t)(h * 64 + row) * D_ + c;

    f32x4 acc[4] = {};

    for (int k0 = 0; k0 < D_; k0 += 128) {
        // stage x tile: 32 floats/thread -> 32 bf16
        {
            const float* g = xg0 + k0;
            float4 f[8];
            #pragma unroll
            for (int j = 0; j < 8; ++j) f[j] = *(const float4*)(g + j * 4);
            #pragma unroll
            for (int j = 0; j < 4; ++j) {
                u16x8 o; pack8(f[j * 2], f[j * 2 + 1], o);
                *(u16x8*)&As[row][c + j * 8] = o;
            }
        }
        // stage Wq tile
        {
            const float* g = wg0 + k0;
            float4 f[8];
            #pragma unroll
            for (int j = 0; j < 8; ++j) f[j] = *(const float4*)(g + j * 4);
            #pragma unroll
            for (int j = 0; j < 4; ++j) {
                u16x8 o; pack8(f[j * 2], f[j * 2 + 1], o);
                *(u16x8*)&Bs[row][c + j * 8] = o;
            }
        }
        __syncthreads();

        #pragma unroll
        for (int kc = 0; kc < 4; ++kc) {
            const bf16x8 af = *(const bf16x8*)&As[w * 16 + l15][kc * 32 + l4 * 8];
            #pragma unroll
            for (int nt = 0; nt < 4; ++nt) {
                const bf16x8 bfr = *(const bf16x8*)&Bs[nt * 16 + l15][kc * 32 + l4 * 8];
                acc[nt] = __builtin_amdgcn_mfma_f32_16x16x32_bf16(af, bfr, acc[nt], 0, 0, 0);
            }
        }
        __syncthreads();
    }

    const float qscale = 1.0f / 32.0f;    // 1/sqrt(D)
    #pragma unroll
    for (int nt = 0; nt < 4; ++nt) {
        const int dh = nt * 16 + l15;
        #pragma unroll
        for (int r = 0; r < 4; ++r) {
            const int m = m0 + w * 16 + l4 * 4 + r;
            const int b = m >> 11, t = m & 2047;
            qb[(((size_t)b * H_ + h) * T_ + t) * DH_ + dh] = f2bf(acc[nt][r] * qscale);
        }
    }
}

// ---------------------------------------------------------------------------
// Launch 2: transposed-S MFMA flash attention + residual (R6 exact).
// 64 q-rows/block (4 waves x 16 rows), 1024 blocks, heavy tiles first.
// S^T = K*Q^T (softmax: 1 scalar/lane + 2 shfls). P^T stays in registers
// (S^T C-layout == K=16 B-operand layout). O^T = V^T * P^T.
// Double-buffered K/V, stride 72 (144 B rows: 16B-aligned), 1 barrier/iter.
// ---------------------------------------------------------------------------
__global__ __launch_bounds__(256, 4) void attn_kernel(
    const unsigned short* __restrict__ qb,   // [B,H,T,DH] bf16, pre-scaled 1/32
    const unsigned short* __restrict__ kb,   // [B,H,T,DH] bf16
    const unsigned short* __restrict__ vt,   // [B,H,DH,T] bf16
    const float* __restrict__ xg,            // [B,T,D] fp32 (residual)
    float* __restrict__ out)                 // [B,T,D] fp32
{
    __shared__ unsigned short Ks[2][64][72];   // [key][dh]
    __shared__ unsigned short Vs[2][64][72];   // [dh][key]

    const int tid = threadIdx.x;
    const int lane = tid & 63;
    const int w = tid >> 6;
    const int l15 = lane & 15, l4 = lane >> 4;
    const int bi = blockIdx.x;
    const int qt = 31 - (bi >> 5);           // heavy q-tiles dispatch first
    const int hb = bi & 31;
    const int h = hb & 15, b = hb >> 4;
    const int q0 = qt * 64;
    const size_t bh = (size_t)b * H_ + h;

    // Q fragments (B-operand: lane l15 = qrow, k = dh); one-time load
    bf16x8 qf[2];
    #pragma unroll
    for (int kc = 0; kc < 2; ++kc)
        qf[kc] = *(const bf16x8*)(qb + (bh * T_ + q0 + w * 16 + l15) * DH_ + kc * 32 + l4 * 8);

    f32x4 o_acc[4] = {};                     // O^T: dh = mt*16+l4*4+r, qrow = l15
    float m_i = -INFINITY, l_i = 0.0f;

    const int srow = tid >> 2;               // staging 0..63
    const int scol = (tid & 3) * 16;

    // stage tile j0=0 into buffer 0
    {
        const unsigned short* gk = kb + (bh * T_ + srow) * DH_ + scol;
        *(uint4*)&Ks[0][srow][scol] = *(const uint4*)gk;
        *(uint4*)&Ks[0][srow][scol + 8] = *(const uint4*)(gk + 8);
        const unsigned short* gv = vt + (bh * DH_ + srow) * T_ + scol;
        *(uint4*)&Vs[0][srow][scol] = *(const uint4*)gv;
        *(uint4*)&Vs[0][srow][scol + 8] = *(const uint4*)(gv + 8);
    }
    __syncthreads();

    int p = 0;
    for (int j0 = 0; j0 <= q0; j0 += 64) {
        // prefetch next tile into registers (valid-but-discarded addr on last)
        const int jn = (j0 + 64 <= q0) ? j0 + 64 : 0;
        uint4 kr0, kr1, vr0, vr1;
        {
            const unsigned short* gk = kb + (bh * T_ + jn + srow) * DH_ + scol;
            kr0 = *(const uint4*)gk;
            kr1 = *(const uint4*)(gk + 8);
            const unsigned short* gv = vt + (bh * DH_ + srow) * T_ + jn + scol;
            vr0 = *(const uint4*)gv;
            vr1 = *(const uint4*)(gv + 8);
        }

        // S^T = K * Q^T : st[nt] keys nt*16 + l4*4+r, qrow = w*16+l15
        f32x4 st[4] = {};
        #pragma unroll
        for (int kc = 0; kc < 2; ++kc) {
            #pragma unroll
            for (int nt = 0; nt < 4; ++nt) {
                const bf16x8 kf = *(const bf16x8*)&Ks[p][nt * 16 + l15][kc * 32 + l4 * 8];
                st[nt] = __builtin_amdgcn_mfma_f32_16x16x32_bf16(kf, qf[kc], st[nt], 0, 0, 0);
            }
        }

        // causal mask (diagonal tile only)
        if (j0 == q0) {
            const int thr = w * 16 + l15 - l4 * 4;   // mask if nt*16+r > thr
            #pragma unroll
            for (int nt = 0; nt < 4; ++nt)
                #pragma unroll
                for (int r = 0; r < 4; ++r)
                    if (nt * 16 + r > thr) st[nt][r] = -INFINITY;
        }

        // online softmax: 16 in-lane values + 2-shfl butterfly over l4
        float rm = -INFINITY;
        #pragma unroll
        for (int nt = 0; nt < 4; ++nt)
            #pragma unroll
            for (int r = 0; r < 4; ++r) rm = fmaxf(rm, st[nt][r]);
        rm = fmaxf(rm, __shfl_xor(rm, 16));
        rm = fmaxf(rm, __shfl_xor(rm, 32));
        const float mn = fmaxf(m_i, rm);
        const float alpha = __expf(m_i - mn);
        float rs = 0.0f;
        #pragma unroll
        for (int nt = 0; nt < 4; ++nt)
            #pragma unroll
            for (int r = 0; r < 4; ++r) {
                const float pv = __expf(st[nt][r] - mn);
                st[nt][r] = pv;
                rs += pv;
            }
        rs += __shfl_xor(rs, 16);
        rs += __shfl_xor(rs, 32);
        l_i = l_i * alpha + rs;
        m_i = mn;
        #pragma unroll
        for (int mt = 0; mt < 4; ++mt)
            #pragma unroll
            for (int r = 0; r < 4; ++r) o_acc[mt][r] *= alpha;

        // pack P^T into K=16 B-frags (v_perm truncation, 2 vals/op)
        bf16x4 pf[4];
        #pragma unroll
        for (int nt = 0; nt < 4; ++nt) {
            union { unsigned int u[2]; bf16x4 s; } cv;
            cv.u[0] = __builtin_amdgcn_perm(__float_as_uint(st[nt][1]),
                                            __float_as_uint(st[nt][0]), 0x07060302u);
            cv.u[1] = __builtin_amdgcn_perm(__float_as_uint(st[nt][3]),
                                            __float_as_uint(st[nt][2]), 0x07060302u);
            pf[nt] = cv.s;
        }

        // O^T += V^T * P^T  (A = V^T from LDS, B = P^T in registers)
        #pragma unroll
        for (int c = 0; c < 4; ++c) {
            #pragma unroll
            for (int mt = 0; mt < 4; ++mt) {
                const bf16x4 vf = *(const bf16x4*)&Vs[p][mt * 16 + l15][c * 16 + l4 * 4];
                o_acc[mt] = mfma16(vf, pf[c], o_acc[mt]);
            }
        }

        // write prefetched tile to the other buffer, single barrier
        *(uint4*)&Ks[p ^ 1][srow][scol] = kr0;
        *(uint4*)&Ks[p ^ 1][srow][scol + 8] = kr1;
        *(uint4*)&Vs[p ^ 1][srow][scol] = vr0;
        *(uint4*)&Vs[p ^ 1][srow][scol + 8] = vr1;
        __syncthreads();
        p ^= 1;
    }

    // epilogue: out = x + O^T / l   (dh = mt*16 + l4*4+r, qrow = l15)
    const float inv = 1.0f / l_i;
    const int qrow = q0 + w * 16 + l15;
    #pragma unroll
    for (int mt = 0; mt < 4; ++mt) {
        #pragma unroll
        for (int r = 0; r < 4; ++r) {
            const int d = h * DH_ + mt * 16 + l4 * 4 + r;
            const size_t off = ((size_t)b * T_ + qrow) * D_ + d;
            out[off] = xg[off] + o_acc[mt][r] * inv;
        }
    }
}

extern "C" void kernel_launch(void* const* d_in, const int* in_sizes, int n_in,
                              void* d_out, int out_size, void* d_ws, size_t ws_size,
                              hipStream_t stream) {
    const float* x  = (const float*)d_in[0];
    const float* k  = (const float*)d_in[1];
    const float* v  = (const float*)d_in[2];
    const float* Wq = (const float*)d_in[3];
    float* out = (float*)d_out;

    const size_t NE = (size_t)B_ * H_ * T_ * DH_;   // 4M elements
    unsigned short* kb = (unsigned short*)d_ws;     // 8 MB
    unsigned short* vt = kb + NE;                   // 8 MB
    unsigned short* qb = vt + NE;                   // 8 MB

    fused_prep_qproj<<<2560, 256, 0, stream>>>(k, v, x, Wq, kb, vt, qb);
    attn_kernel<<<1024, 256, 0, stream>>>(qb, kb, vt, x, out);
}

// Round 10
// 169.210 us; speedup vs baseline: 1.6504x; 1.1643x over previous
//
#include <hip/hip_runtime.h>
#include <hip/hip_bf16.h>

#define B_ 2
#define T_ 2048
#define D_ 1024
#define H_ 16
#define DH_ 64

typedef __attribute__((ext_vector_type(8))) short bf16x8;
typedef __attribute__((ext_vector_type(4))) short bf16x4;
typedef __attribute__((ext_vector_type(4))) float f32x4;
typedef __attribute__((ext_vector_type(8))) unsigned short u16x8;

__device__ __forceinline__ unsigned short f2bf(float f) {   // RNE fp32->bf16
    unsigned int u = __float_as_uint(f);
    return (unsigned short)((u + 0x7FFFu + ((u >> 16) & 1u)) >> 16);
}

__device__ __forceinline__ void pack8(const float4& a, const float4& b, u16x8& o) {
    o[0] = f2bf(a.x); o[1] = f2bf(a.y); o[2] = f2bf(a.z); o[3] = f2bf(a.w);
    o[4] = f2bf(b.x); o[5] = f2bf(b.y); o[6] = f2bf(b.z); o[7] = f2bf(b.w);
}

// K=16 bf16 MFMA; guard so the host pass never touches the builtin.
__device__ __forceinline__ f32x4 mfma16(bf16x4 a, bf16x4 b, f32x4 c) {
#if defined(__HIP_DEVICE_COMPILE__)
    return __builtin_amdgcn_mfma_f32_16x16x16bf16_1k(a, b, c, 0, 0, 0);
#else
    return c;
#endif
}

// ---------------------------------------------------------------------------
// Launch 1: pure streaming conversions.
//   [0,512)    : k fp32 -> kb bf16 (32 elems/thread)
//   [512,1536) : v[b,h,t,dh] -> vt[b,h,dh,t] bf16 (64x64 LDS transpose)
// ---------------------------------------------------------------------------
__global__ __launch_bounds__(256) void conv_kernel(
    const float* __restrict__ k, const float* __restrict__ v,
    unsigned short* __restrict__ kb, unsigned short* __restrict__ vt)
{
    __shared__ float Ts[64][65];
    const int tid = threadIdx.x;
    const int bi = blockIdx.x;

    if (bi < 512) {                       // ---- k conversion ----
        const float* src = k + ((size_t)bi * 256 + tid) * 32;
        unsigned short* dst = kb + ((size_t)bi * 256 + tid) * 32;
        #pragma unroll
        for (int u = 0; u < 4; ++u) {
            const float4 a = *(const float4*)(src + u * 8);
            const float4 b = *(const float4*)(src + u * 8 + 4);
            u16x8 o; pack8(a, b, o);
            *(u16x8*)(dst + u * 8) = o;
        }
        return;
    }

    // ---- v transpose+convert ----
    const int idx = bi - 512;
    const int t0 = (idx & 31) * 64;
    const int hb = idx >> 5;
    const size_t bh = (size_t)(hb >> 4) * H_ + (hb & 15);
    #pragma unroll
    for (int u = 0; u < 4; ++u) {
        const int tr = u * 16 + (tid >> 4);
        const int dc = (tid & 15) * 4;
        const float4 r = *(const float4*)(v + (bh * T_ + t0 + tr) * DH_ + dc);
        Ts[tr][dc + 0] = r.x; Ts[tr][dc + 1] = r.y;
        Ts[tr][dc + 2] = r.z; Ts[tr][dc + 3] = r.w;
    }
    __syncthreads();
    #pragma unroll
    for (int u = 0; u < 4; ++u) {
        const int dh = u * 16 + (tid >> 4);
        const int tc = (tid & 15) * 4;
        ushort4 o;
        o.x = f2bf(Ts[tc + 0][dh]); o.y = f2bf(Ts[tc + 1][dh]);
        o.z = f2bf(Ts[tc + 2][dh]); o.w = f2bf(Ts[tc + 3][dh]);
        *(ushort4*)(vt + (bh * DH_ + dh) * T_ + t0 + tc) = o;
    }
}

// ---------------------------------------------------------------------------
// Launch 2: mega-attention (qproj fused in, no global barrier, no qb traffic).
// Block (qt,h,b), 64 q-rows, 4 waves x 16 rows, 1024 blocks, heavy qt first.
//
// Phase 1: Q^T = Wq_h * x^T via 16-iter LDS-staged GEMM (fp32 global ->
//   f2bf -> LDS bf16; fragments ONLY from LDS). acc C-layout = Q^T
//   [dh = w*16+l4*4+r][qrow = nt*16+l15]; bounce through Qs (overlaid on
//   dead Vs1 region) to get B-operand Q fragments. Scale 1/sqrt(D) folded.
// Phase 2: R6 transposed-S flash loop, double-buffered K/V, stride 72,
//   1 barrier/iter, P^T in registers, O^T = V^T * P^T, fused residual.
// ---------------------------------------------------------------------------
__global__ __launch_bounds__(256, 4) void mega_attn(
    const float* __restrict__ xg,            // [B,T,D] fp32
    const float* __restrict__ Wq,            // [D,D]   fp32
    const unsigned short* __restrict__ kb,   // [B,H,T,DH] bf16
    const unsigned short* __restrict__ vt,   // [B,H,DH,T] bf16
    float* __restrict__ out)                 // [B,T,D] fp32
{
    __shared__ __align__(16) char lds_raw[36864];
    // phase 2 layout
    unsigned short (*Ks0)[72] = (unsigned short(*)[72])(lds_raw);
    unsigned short (*Ks1)[72] = (unsigned short(*)[72])(lds_raw + 9216);
    unsigned short (*Vs0)[72] = (unsigned short(*)[72])(lds_raw + 18432);
    unsigned short (*Vs1)[72] = (unsigned short(*)[72])(lds_raw + 27648);
    // phase 1 overlay (Ws,Xs die before Ks0/Ks1 staging; Qs dies before
    // the first Vs1 write, which happens after a barrier that follows the
    // qf register read)
    unsigned short (*Ws)[72] = (unsigned short(*)[72])(lds_raw);           // [dh][k]
    unsigned short (*Xs)[72] = (unsigned short(*)[72])(lds_raw + 9216);    // [qrow][k]
    unsigned short (*Qs)[72] = (unsigned short(*)[72])(lds_raw + 27648);   // [qrow][dh]

    const int tid = threadIdx.x;
    const int lane = tid & 63;
    const int w = tid >> 6;
    const int l15 = lane & 15, l4 = lane >> 4;
    const int bi = blockIdx.x;
    const int qt = 31 - (bi >> 5);           // heavy q-tiles dispatch first
    const int hb = bi & 31;
    const int h = hb & 15, b = hb >> 4;
    const int q0 = qt * 64;
    const size_t bh = (size_t)b * H_ + h;

    // ---- Phase 1: Q^T tile build ----
    {
        const int row = tid >> 2;            // staging row 0..63
        const int cf  = (tid & 3) * 16;      // k-col (16 floats/thread/tile)
        const float* xg0 = xg + ((size_t)b * T_ + q0 + row) * D_ + cf;
        const float* wg0 = Wq + (size_t)(h * 64 + row) * D_ + cf;

        f32x4 acc[4] = {};
        for (int k0 = 0; k0 < D_; k0 += 64) {
            {
                const float* g = xg0 + k0;
                u16x8 p0, p1;
                pack8(*(const float4*)(g), *(const float4*)(g + 4), p0);
                pack8(*(const float4*)(g + 8), *(const float4*)(g + 12), p1);
                *(u16x8*)&Xs[row][cf] = p0;
                *(u16x8*)&Xs[row][cf + 8] = p1;
                const float* gw = wg0 + k0;
                pack8(*(const float4*)(gw), *(const float4*)(gw + 4), p0);
                pack8(*(const float4*)(gw + 8), *(const float4*)(gw + 12), p1);
                *(u16x8*)&Ws[row][cf] = p0;
                *(u16x8*)&Ws[row][cf + 8] = p1;
            }
            __syncthreads();
            #pragma unroll
            for (int kc = 0; kc < 2; ++kc) {
                const bf16x8 wf = *(const bf16x8*)&Ws[w * 16 + l15][kc * 32 + l4 * 8];
                #pragma unroll
                for (int nt = 0; nt < 4; ++nt) {
                    const bf16x8 xf = *(const bf16x8*)&Xs[nt * 16 + l15][kc * 32 + l4 * 8];
                    acc[nt] = __builtin_amdgcn_mfma_f32_16x16x32_bf16(wf, xf, acc[nt], 0, 0, 0);
                }
            }
            __syncthreads();
        }
        // acc[nt][r] = Q^T[dh = w*16 + l4*4 + r][qrow = nt*16 + l15]
        const float qscale = 1.0f / 32.0f;   // 1/sqrt(D)
        #pragma unroll
        for (int nt = 0; nt < 4; ++nt) {
            ushort4 o;
            o.x = f2bf(acc[nt][0] * qscale); o.y = f2bf(acc[nt][1] * qscale);
            o.z = f2bf(acc[nt][2] * qscale); o.w = f2bf(acc[nt][3] * qscale);
            *(ushort4*)&Qs[nt * 16 + l15][w * 16 + l4 * 4] = o;
        }
    }
    __syncthreads();   // all Qs writes visible (cross-wave)

    // Q B-fragments: lane l15 = qrow (w*16+l15), k = dh
    bf16x8 qf[2];
    #pragma unroll
    for (int kc = 0; kc < 2; ++kc)
        qf[kc] = *(const bf16x8*)&Qs[w * 16 + l15][kc * 32 + l4 * 8];

    f32x4 o_acc[4] = {};                     // O^T: dh = mt*16+l4*4+r, qrow = l15
    float m_i = -INFINITY, l_i = 0.0f;

    const int srow = tid >> 2;               // staging 0..63
    const int scol = (tid & 3) * 16;

    // stage tile j0=0 into buffer 0 (Ks0/Vs0 don't overlap Qs)
    {
        const unsigned short* gk = kb + (bh * T_ + srow) * DH_ + scol;
        *(uint4*)&Ks0[srow][scol] = *(const uint4*)gk;
        *(uint4*)&Ks0[srow][scol + 8] = *(const uint4*)(gk + 8);
        const unsigned short* gv = vt + (bh * DH_ + srow) * T_ + scol;
        *(uint4*)&Vs0[srow][scol] = *(const uint4*)gv;
        *(uint4*)&Vs0[srow][scol + 8] = *(const uint4*)(gv + 8);
    }
    __syncthreads();   // also orders qf reads before any later Vs1 write

    int p = 0;
    for (int j0 = 0; j0 <= q0; j0 += 64) {
        unsigned short (*Ksp)[72] = p ? Ks1 : Ks0;
        unsigned short (*Vsp)[72] = p ? Vs1 : Vs0;
        unsigned short (*Ksn)[72] = p ? Ks0 : Ks1;
        unsigned short (*Vsn)[72] = p ? Vs0 : Vs1;

        // prefetch next tile into registers (valid-but-discarded addr on last)
        const int jn = (j0 + 64 <= q0) ? j0 + 64 : 0;
        uint4 kr0, kr1, vr0, vr1;
        {
            const unsigned short* gk = kb + (bh * T_ + jn + srow) * DH_ + scol;
            kr0 = *(const uint4*)gk;
            kr1 = *(const uint4*)(gk + 8);
            const unsigned short* gv = vt + (bh * DH_ + srow) * T_ + jn + scol;
            vr0 = *(const uint4*)gv;
            vr1 = *(const uint4*)(gv + 8);
        }

        // S^T = K * Q^T : st[nt] keys nt*16 + l4*4+r, qrow = w*16+l15
        f32x4 st[4] = {};
        #pragma unroll
        for (int kc = 0; kc < 2; ++kc) {
            #pragma unroll
            for (int nt = 0; nt < 4; ++nt) {
                const bf16x8 kf = *(const bf16x8*)&Ksp[nt * 16 + l15][kc * 32 + l4 * 8];
                st[nt] = __builtin_amdgcn_mfma_f32_16x16x32_bf16(kf, qf[kc], st[nt], 0, 0, 0);
            }
        }

        // causal mask (diagonal tile only)
        if (j0 == q0) {
            const int thr = w * 16 + l15 - l4 * 4;   // mask if nt*16+r > thr
            #pragma unroll
            for (int nt = 0; nt < 4; ++nt)
                #pragma unroll
                for (int r = 0; r < 4; ++r)
                    if (nt * 16 + r > thr) st[nt][r] = -INFINITY;
        }

        // online softmax: 16 in-lane values + 2-shfl butterfly over l4
        float rm = -INFINITY;
        #pragma unroll
        for (int nt = 0; nt < 4; ++nt)
            #pragma unroll
            for (int r = 0; r < 4; ++r) rm = fmaxf(rm, st[nt][r]);
        rm = fmaxf(rm, __shfl_xor(rm, 16));
        rm = fmaxf(rm, __shfl_xor(rm, 32));
        const float mn = fmaxf(m_i, rm);
        const float alpha = __expf(m_i - mn);
        float rs = 0.0f;
        #pragma unroll
        for (int nt = 0; nt < 4; ++nt)
            #pragma unroll
            for (int r = 0; r < 4; ++r) {
                const float pv = __expf(st[nt][r] - mn);
                st[nt][r] = pv;
                rs += pv;
            }
        rs += __shfl_xor(rs, 16);
        rs += __shfl_xor(rs, 32);
        l_i = l_i * alpha + rs;
        m_i = mn;
        #pragma unroll
        for (int mt = 0; mt < 4; ++mt)
            #pragma unroll
            for (int r = 0; r < 4; ++r) o_acc[mt][r] *= alpha;

        // pack P^T into K=16 B-frags (v_perm truncation, 2 vals/op)
        bf16x4 pf[4];
        #pragma unroll
        for (int nt = 0; nt < 4; ++nt) {
            union { unsigned int u[2]; bf16x4 s; } cv;
            cv.u[0] = __builtin_amdgcn_perm(__float_as_uint(st[nt][1]),
                                            __float_as_uint(st[nt][0]), 0x07060302u);
            cv.u[1] = __builtin_amdgcn_perm(__float_as_uint(st[nt][3]),
                                            __float_as_uint(st[nt][2]), 0x07060302u);
            pf[nt] = cv.s;
        }

        // O^T += V^T * P^T  (A = V^T from LDS, B = P^T in registers)
        #pragma unroll
        for (int c = 0; c < 4; ++c) {
            #pragma unroll
            for (int mt = 0; mt < 4; ++mt) {
                const bf16x4 vf = *(const bf16x4*)&Vsp[mt * 16 + l15][c * 16 + l4 * 4];
                o_acc[mt] = mfma16(vf, pf[c], o_acc[mt]);
            }
        }

        // write prefetched tile to the other buffer, single barrier
        *(uint4*)&Ksn[srow][scol] = kr0;
        *(uint4*)&Ksn[srow][scol + 8] = kr1;
        *(uint4*)&Vsn[srow][scol] = vr0;
        *(uint4*)&Vsn[srow][scol + 8] = vr1;
        __syncthreads();
        p ^= 1;
    }

    // epilogue: out = x + O^T / l   (dh = mt*16 + l4*4+r, qrow = l15)
    const float inv = 1.0f / l_i;
    const int qrow = q0 + w * 16 + l15;
    #pragma unroll
    for (int mt = 0; mt < 4; ++mt) {
        #pragma unroll
        for (int r = 0; r < 4; ++r) {
            const int d = h * DH_ + mt * 16 + l4 * 4 + r;
            const size_t off = ((size_t)b * T_ + qrow) * D_ + d;
            out[off] = xg[off] + o_acc[mt][r] * inv;
        }
    }
}

extern "C" void kernel_launch(void* const* d_in, const int* in_sizes, int n_in,
                              void* d_out, int out_size, void* d_ws, size_t ws_size,
                              hipStream_t stream) {
    const float* x  = (const float*)d_in[0];
    const float* k  = (const float*)d_in[1];
    const float* v  = (const float*)d_in[2];
    const float* Wq = (const float*)d_in[3];
    float* out = (float*)d_out;

    const size_t NE = (size_t)B_ * H_ * T_ * DH_;   // 4M elements
    unsigned short* kb = (unsigned short*)d_ws;     // 8 MB
    unsigned short* vt = kb + NE;                   // 8 MB

    conv_kernel<<<1536, 256, 0, stream>>>(k, v, kb, vt);
    mega_attn<<<1024, 256, 0, stream>>>(x, Wq, kb, vt, out);
}

// Round 11
// 156.890 us; speedup vs baseline: 1.7800x; 1.0785x over previous
//
#include <hip/hip_runtime.h>
#include <hip/hip_bf16.h>

#define B_ 2
#define T_ 2048
#define D_ 1024
#define H_ 16
#define DH_ 64

typedef __attribute__((ext_vector_type(8))) short bf16x8;
typedef __attribute__((ext_vector_type(4))) short bf16x4;
typedef __attribute__((ext_vector_type(4))) float f32x4;
typedef __attribute__((ext_vector_type(8))) unsigned short u16x8;

__device__ __forceinline__ unsigned short f2bf(float f) {   // RNE fp32->bf16
    unsigned int u = __float_as_uint(f);
    return (unsigned short)((u + 0x7FFFu + ((u >> 16) & 1u)) >> 16);
}

__device__ __forceinline__ void pack8(const float4& a, const float4& b, u16x8& o) {
    o[0] = f2bf(a.x); o[1] = f2bf(a.y); o[2] = f2bf(a.z); o[3] = f2bf(a.w);
    o[4] = f2bf(b.x); o[5] = f2bf(b.y); o[6] = f2bf(b.z); o[7] = f2bf(b.w);
}

// K=16 bf16 MFMA; guard so the host pass never touches the builtin.
__device__ __forceinline__ f32x4 mfma16(bf16x4 a, bf16x4 b, f32x4 c) {
#if defined(__HIP_DEVICE_COMPILE__)
    return __builtin_amdgcn_mfma_f32_16x16x16bf16_1k(a, b, c, 0, 0, 0);
#else
    return c;
#endif
}

// ---------------------------------------------------------------------------
// Launch 1: pure streaming conversions (independent blocks).
//   [0,512)    : k  fp32 -> kb  bf16 (32 elems/thread)
//   [512,1024) : x  fp32 -> xb  bf16
//   [1024,1152): Wq fp32 -> wqb bf16
//   [1152,2176): v[b,h,t,dh] -> vt[b,h,dh,t] bf16 (64x64 LDS transpose)
// ---------------------------------------------------------------------------
__global__ __launch_bounds__(256) void conv_kernel(
    const float* __restrict__ k, const float* __restrict__ v,
    const float* __restrict__ x, const float* __restrict__ Wq,
    unsigned short* __restrict__ kb, unsigned short* __restrict__ vt,
    unsigned short* __restrict__ xb, unsigned short* __restrict__ wqb)
{
    __shared__ float Ts[64][65];
    const int tid = threadIdx.x;
    const int bi = blockIdx.x;

    if (bi < 1152) {                      // ---- flat conversions ----
        const float* src;
        unsigned short* dst;
        if (bi < 512)       { src = k  + ((size_t)bi * 256 + tid) * 32;
                              dst = kb  + ((size_t)bi * 256 + tid) * 32; }
        else if (bi < 1024) { src = x  + ((size_t)(bi - 512) * 256 + tid) * 32;
                              dst = xb  + ((size_t)(bi - 512) * 256 + tid) * 32; }
        else                { src = Wq + ((size_t)(bi - 1024) * 256 + tid) * 32;
                              dst = wqb + ((size_t)(bi - 1024) * 256 + tid) * 32; }
        #pragma unroll
        for (int u = 0; u < 4; ++u) {
            const float4 a = *(const float4*)(src + u * 8);
            const float4 b = *(const float4*)(src + u * 8 + 4);
            u16x8 o; pack8(a, b, o);
            *(u16x8*)(dst + u * 8) = o;
        }
        return;
    }

    // ---- v transpose+convert ----
    const int idx = bi - 1152;
    const int t0 = (idx & 31) * 64;
    const int hb = idx >> 5;
    const size_t bh = (size_t)(hb >> 4) * H_ + (hb & 15);
    #pragma unroll
    for (int u = 0; u < 4; ++u) {
        const int tr = u * 16 + (tid >> 4);
        const int dc = (tid & 15) * 4;
        const float4 r = *(const float4*)(v + (bh * T_ + t0 + tr) * DH_ + dc);
        Ts[tr][dc + 0] = r.x; Ts[tr][dc + 1] = r.y;
        Ts[tr][dc + 2] = r.z; Ts[tr][dc + 3] = r.w;
    }
    __syncthreads();
    #pragma unroll
    for (int u = 0; u < 4; ++u) {
        const int dh = u * 16 + (tid >> 4);
        const int tc = (tid & 15) * 4;
        ushort4 o;
        o.x = f2bf(Ts[tc + 0][dh]); o.y = f2bf(Ts[tc + 1][dh]);
        o.z = f2bf(Ts[tc + 2][dh]); o.w = f2bf(Ts[tc + 3][dh]);
        *(ushort4*)(vt + (bh * DH_ + dh) * T_ + t0 + tc) = o;
    }
}

// ---------------------------------------------------------------------------
// Launch 2: mega-attention (qproj fused). Block (qt,h,b), 64 q-rows,
// 4 waves x 16 rows, 1024 blocks, heavy qt first.
//
// Phase 1: Q^T = Wq_h * x^T, bf16 inputs staged as pure uint4 copies,
//   double-buffered (1 barrier/iter, 16 iters). acc C-layout = Q^T
//   [dh = w*16+l4*4+r][qrow = nt*16+l15]; bounced through Qs (overlaid on
//   the dead Xs1 region after the final barrier) -> B-operand Q fragments.
// Phase 2: transposed-S flash loop (R6), double-buffered K/V, stride 72,
//   1 barrier/iter, P^T in registers, O^T = V^T * P^T, fused residual.
//
// LDS regions (36864 B): phase1 Ws0=0, Xs0=9216, Ws1=18432, Xs1=27648;
// Qs=27648; phase2 Ks0=0, Ks1=9216, Vs0=18432, Vs1=27648. All reuses are
// barrier-separated (checked: Qs write after final phase-1 barrier; Vs1
// first written after the post-staging barrier that follows the qf read).
// ---------------------------------------------------------------------------
__global__ __launch_bounds__(256, 4) void mega_attn(
    const unsigned short* __restrict__ xb,   // [B,T,D]   bf16
    const unsigned short* __restrict__ wqb,  // [D,D]     bf16
    const unsigned short* __restrict__ kb,   // [B,H,T,DH] bf16
    const unsigned short* __restrict__ vt,   // [B,H,DH,T] bf16
    const float* __restrict__ xg,            // [B,T,D] fp32 (residual)
    float* __restrict__ out)                 // [B,T,D] fp32
{
    __shared__ __align__(16) char lds_raw[36864];
    unsigned short (*Ws0)[72] = (unsigned short(*)[72])(lds_raw);
    unsigned short (*Xs0)[72] = (unsigned short(*)[72])(lds_raw + 9216);
    unsigned short (*Ws1)[72] = (unsigned short(*)[72])(lds_raw + 18432);
    unsigned short (*Xs1)[72] = (unsigned short(*)[72])(lds_raw + 27648);
    unsigned short (*Qs)[72]  = (unsigned short(*)[72])(lds_raw + 27648);
    unsigned short (*Ks0)[72] = (unsigned short(*)[72])(lds_raw);
    unsigned short (*Ks1)[72] = (unsigned short(*)[72])(lds_raw + 9216);
    unsigned short (*Vs0)[72] = (unsigned short(*)[72])(lds_raw + 18432);
    unsigned short (*Vs1)[72] = (unsigned short(*)[72])(lds_raw + 27648);

    const int tid = threadIdx.x;
    const int lane = tid & 63;
    const int w = tid >> 6;
    const int l15 = lane & 15, l4 = lane >> 4;
    const int bi = blockIdx.x;
    const int qt = 31 - (bi >> 5);           // heavy q-tiles dispatch first
    const int hb = bi & 31;
    const int h = hb & 15, b = hb >> 4;
    const int q0 = qt * 64;
    const size_t bh = (size_t)b * H_ + h;

    const int srow = tid >> 2;               // staging row 0..63
    const int scol = (tid & 3) * 16;         // staging col (shorts)

    // ---- Phase 1: Q^T tile build (bf16 staged, dbuf, 1 barrier/iter) ----
    f32x4 acc[4] = {};
    {
        const unsigned short* xg0 = xb  + ((size_t)b * T_ + q0 + srow) * D_ + scol;
        const unsigned short* wg0 = wqb + (size_t)(h * 64 + srow) * D_ + scol;

        // stage iter 0 into buffer 0
        uint4 xr0 = *(const uint4*)(xg0);
        uint4 xr1 = *(const uint4*)(xg0 + 8);
        uint4 wr0 = *(const uint4*)(wg0);
        uint4 wr1 = *(const uint4*)(wg0 + 8);
        *(uint4*)&Xs0[srow][scol] = xr0;
        *(uint4*)&Xs0[srow][scol + 8] = xr1;
        *(uint4*)&Ws0[srow][scol] = wr0;
        *(uint4*)&Ws0[srow][scol + 8] = wr1;
        __syncthreads();

        int p = 0;
        for (int it = 0; it < 16; ++it) {
            if (it < 15) {
                const int kk = (it + 1) * 64;
                xr0 = *(const uint4*)(xg0 + kk);
                xr1 = *(const uint4*)(xg0 + kk + 8);
                wr0 = *(const uint4*)(wg0 + kk);
                wr1 = *(const uint4*)(wg0 + kk + 8);
            }
            unsigned short (*Wp)[72] = p ? Ws1 : Ws0;
            unsigned short (*Xp)[72] = p ? Xs1 : Xs0;
            #pragma unroll
            for (int kc = 0; kc < 2; ++kc) {
                const bf16x8 wf = *(const bf16x8*)&Wp[w * 16 + l15][kc * 32 + l4 * 8];
                #pragma unroll
                for (int nt = 0; nt < 4; ++nt) {
                    const bf16x8 xf = *(const bf16x8*)&Xp[nt * 16 + l15][kc * 32 + l4 * 8];
                    acc[nt] = __builtin_amdgcn_mfma_f32_16x16x32_bf16(wf, xf, acc[nt], 0, 0, 0);
                }
            }
            if (it < 15) {
                unsigned short (*Wn)[72] = p ? Ws0 : Ws1;
                unsigned short (*Xn)[72] = p ? Xs0 : Xs1;
                *(uint4*)&Xn[srow][scol] = xr0;
                *(uint4*)&Xn[srow][scol + 8] = xr1;
                *(uint4*)&Wn[srow][scol] = wr0;
                *(uint4*)&Wn[srow][scol + 8] = wr1;
                __syncthreads();
                p ^= 1;
            }
        }
    }
    __syncthreads();   // final phase-1 buffer (Ws1/Xs1) fully consumed

    // Qs write: acc[nt][r] = Q^T[dh = w*16+l4*4+r][qrow = nt*16+l15]
    {
        const float qscale = 1.0f / 32.0f;   // 1/sqrt(D)
        #pragma unroll
        for (int nt = 0; nt < 4; ++nt) {
            ushort4 o;
            o.x = f2bf(acc[nt][0] * qscale); o.y = f2bf(acc[nt][1] * qscale);
            o.z = f2bf(acc[nt][2] * qscale); o.w = f2bf(acc[nt][3] * qscale);
            *(ushort4*)&Qs[nt * 16 + l15][w * 16 + l4 * 4] = o;
        }
    }
    __syncthreads();   // all Qs writes visible (cross-wave)

    // Q B-fragments: lane l15 = qrow (w*16+l15), k = dh
    bf16x8 qf[2];
    #pragma unroll
    for (int kc = 0; kc < 2; ++kc)
        qf[kc] = *(const bf16x8*)&Qs[w * 16 + l15][kc * 32 + l4 * 8];

    f32x4 o_acc[4] = {};                     // O^T: dh = mt*16+l4*4+r, qrow = l15
    float m_i = -INFINITY, l_i = 0.0f;

    // stage tile j0=0 into buffer 0 (Ks0/Vs0 don't overlap Qs)
    {
        const unsigned short* gk = kb + (bh * T_ + srow) * DH_ + scol;
        *(uint4*)&Ks0[srow][scol] = *(const uint4*)gk;
        *(uint4*)&Ks0[srow][scol + 8] = *(const uint4*)(gk + 8);
        const unsigned short* gv = vt + (bh * DH_ + srow) * T_ + scol;
        *(uint4*)&Vs0[srow][scol] = *(const uint4*)gv;
        *(uint4*)&Vs0[srow][scol + 8] = *(const uint4*)(gv + 8);
    }
    __syncthreads();   // also orders qf reads before any later Vs1 write

    int p = 0;
    for (int j0 = 0; j0 <= q0; j0 += 64) {
        unsigned short (*Ksp)[72] = p ? Ks1 : Ks0;
        unsigned short (*Vsp)[72] = p ? Vs1 : Vs0;
        unsigned short (*Ksn)[72] = p ? Ks0 : Ks1;
        unsigned short (*Vsn)[72] = p ? Vs0 : Vs1;

        // prefetch next tile into registers (valid-but-discarded addr on last)
        const int jn = (j0 + 64 <= q0) ? j0 + 64 : 0;
        uint4 kr0, kr1, vr0, vr1;
        {
            const unsigned short* gk = kb + (bh * T_ + jn + srow) * DH_ + scol;
            kr0 = *(const uint4*)gk;
            kr1 = *(const uint4*)(gk + 8);
            const unsigned short* gv = vt + (bh * DH_ + srow) * T_ + jn + scol;
            vr0 = *(const uint4*)gv;
            vr1 = *(const uint4*)(gv + 8);
        }

        // S^T = K * Q^T : st[nt] keys nt*16 + l4*4+r, qrow = w*16+l15
        f32x4 st[4] = {};
        #pragma unroll
        for (int kc = 0; kc < 2; ++kc) {
            #pragma unroll
            for (int nt = 0; nt < 4; ++nt) {
                const bf16x8 kf = *(const bf16x8*)&Ksp[nt * 16 + l15][kc * 32 + l4 * 8];
                st[nt] = __builtin_amdgcn_mfma_f32_16x16x32_bf16(kf, qf[kc], st[nt], 0, 0, 0);
            }
        }

        // causal mask (diagonal tile only)
        if (j0 == q0) {
            const int thr = w * 16 + l15 - l4 * 4;   // mask if nt*16+r > thr
            #pragma unroll
            for (int nt = 0; nt < 4; ++nt)
                #pragma unroll
                for (int r = 0; r < 4; ++r)
                    if (nt * 16 + r > thr) st[nt][r] = -INFINITY;
        }

        // online softmax: 16 in-lane values + 2-shfl butterfly over l4
        float rm = -INFINITY;
        #pragma unroll
        for (int nt = 0; nt < 4; ++nt)
            #pragma unroll
            for (int r = 0; r < 4; ++r) rm = fmaxf(rm, st[nt][r]);
        rm = fmaxf(rm, __shfl_xor(rm, 16));
        rm = fmaxf(rm, __shfl_xor(rm, 32));
        const float mn = fmaxf(m_i, rm);
        const float alpha = __expf(m_i - mn);
        float rs = 0.0f;
        #pragma unroll
        for (int nt = 0; nt < 4; ++nt)
            #pragma unroll
            for (int r = 0; r < 4; ++r) {
                const float pv = __expf(st[nt][r] - mn);
                st[nt][r] = pv;
                rs += pv;
            }
        rs += __shfl_xor(rs, 16);
        rs += __shfl_xor(rs, 32);
        l_i = l_i * alpha + rs;
        m_i = mn;
        #pragma unroll
        for (int mt = 0; mt < 4; ++mt)
            #pragma unroll
            for (int r = 0; r < 4; ++r) o_acc[mt][r] *= alpha;

        // pack P^T into K=16 B-frags (v_perm truncation, 2 vals/op)
        bf16x4 pf[4];
        #pragma unroll
        for (int nt = 0; nt < 4; ++nt) {
            union { unsigned int u[2]; bf16x4 s; } cv;
            cv.u[0] = __builtin_amdgcn_perm(__float_as_uint(st[nt][1]),
                                            __float_as_uint(st[nt][0]), 0x07060302u);
            cv.u[1] = __builtin_amdgcn_perm(__float_as_uint(st[nt][3]),
                                            __float_as_uint(st[nt][2]), 0x07060302u);
            pf[nt] = cv.s;
        }

        // O^T += V^T * P^T  (A = V^T from LDS, B = P^T in registers)
        #pragma unroll
        for (int c = 0; c < 4; ++c) {
            #pragma unroll
            for (int mt = 0; mt < 4; ++mt) {
                const bf16x4 vf = *(const bf16x4*)&Vsp[mt * 16 + l15][c * 16 + l4 * 4];
                o_acc[mt] = mfma16(vf, pf[c], o_acc[mt]);
            }
        }

        // write prefetched tile to the other buffer, single barrier
        *(uint4*)&Ksn[srow][scol] = kr0;
        *(uint4*)&Ksn[srow][scol + 8] = kr1;
        *(uint4*)&Vsn[srow][scol] = vr0;
        *(uint4*)&Vsn[srow][scol + 8] = vr1;
        __syncthreads();
        p ^= 1;
    }

    // epilogue: out = x + O^T / l   (dh = mt*16 + l4*4+r, qrow = l15)
    const float inv = 1.0f / l_i;
    const int qrow = q0 + w * 16 + l15;
    #pragma unroll
    for (int mt = 0; mt < 4; ++mt) {
        #pragma unroll
        for (int r = 0; r < 4; ++r) {
            const int d = h * DH_ + mt * 16 + l4 * 4 + r;
            const size_t off = ((size_t)b * T_ + qrow) * D_ + d;
            out[off] = xg[off] + o_acc[mt][r] * inv;
        }
    }
}

extern "C" void kernel_launch(void* const* d_in, const int* in_sizes, int n_in,
                              void* d_out, int out_size, void* d_ws, size_t ws_size,
                              hipStream_t stream) {
    const float* x  = (const float*)d_in[0];
    const float* k  = (const float*)d_in[1];
    const float* v  = (const float*)d_in[2];
    const float* Wq = (const float*)d_in[3];
    float* out = (float*)d_out;

    const size_t NE = (size_t)B_ * H_ * T_ * DH_;   // 4M elements
    unsigned short* kb  = (unsigned short*)d_ws;    // 8 MB
    unsigned short* vt  = kb + NE;                  // 8 MB
    unsigned short* xb  = vt + NE;                  // 8 MB
    unsigned short* wqb = xb + NE;                  // 2 MB

    conv_kernel<<<2176, 256, 0, stream>>>(k, v, x, Wq, kb, vt, xb, wqb);
    mega_attn<<<1024, 256, 0, stream>>>(xb, wqb, kb, vt, x, out);
}